// Round 6
// baseline (69.547 us; speedup 1.0000x reference)
//
#include <hip/hip_runtime.h>
#include <math.h>

#define FOUR_PI     12.566370614359172f
#define INV_FOUR_PI 0.07957747154594767f
#define EG          0.5772156649015329f
#define LN2         0.6931471805599453f
#define CF_         (4.0f / 3.0f)

// Li2(x) = sum_{k>=1} x^k / k^2 ; |x| <= 0.19 here -> 8 terms gives <5e-9 abs err
__device__ __forceinline__ float li2_series(float x) {
    float t = x;
    float s = x;
    t *= x; s = fmaf(t, 0.25f, s);
    t *= x; s = fmaf(t, (1.0f / 9.0f), s);
    t *= x; s = fmaf(t, 0.0625f, s);
    t *= x; s = fmaf(t, 0.04f, s);
    t *= x; s = fmaf(t, (1.0f / 36.0f), s);
    t *= x; s = fmaf(t, (1.0f / 49.0f), s);
    t *= x; s = fmaf(t, 0.015625f, s);
    return s;
}

struct PEConsts {
    float d4[4];        // 4*pi*delta[j]
    float logden[4];    // log(alphaS_i - 4*pi*delta[j])
    float rG[4], rg[4];
    float rb0, rb1;
    float rbp;
    float inv_a0, inv_di;
    float dilog_a0, log1m, coeffs2;
    float kt_coef, log_mu_c;
};

__device__ __forceinline__ void compute_point(const PEConsts& c, float x, float b,
                                              float& eta, float& kg, float& KG, float& Kt) {
    float Lr0 = __logf(x - c.d4[0]) - c.logden[0];
    float Lr1 = __logf(x - c.d4[1]) - c.logden[1];
    float Lr2 = __logf(x - c.d4[2]) - c.logden[2];
    float Lr3 = __logf(x - c.d4[3]) - c.logden[3];

    eta = -0.5f * (c.rG[0] * Lr0 + c.rG[1] * Lr1 + c.rG[2] * Lr2 + c.rG[3] * Lr3);
    kg  = -0.5f * (c.rg[0] * Lr0 + c.rg[1] * Lr1 + c.rg[2] * Lr2 + c.rg[3] * Lr3);

    float aS     = x * INV_FOUR_PI;
    float inv_aS = FOUR_PI / x;

    // line1
    float line1 = 0.25f * c.rG[0] * c.rbp * (inv_aS + (Lr0 - 1.0f) * c.inv_a0)
                + 0.125f * c.rG[0] * c.rb0 * Lr0 * Lr0;
    // line2 (ORDER==1 -> only j=1 term)
    float dilog_aS = li2_series(aS * c.inv_di);
    float line2 = 0.25f * c.coeffs2 * (Lr0 * c.log1m + dilog_aS - c.dilog_a0);
    // line3
    float t1 = 0.5f * c.rb1 * Lr1 * Lr1;
    float t2 = c.rb0 * Lr0 * Lr1;
    float t3 = c.rbp * ((Lr0 - Lr1) * c.inv_di + Lr1 * c.inv_a0);
    float line3 = 0.25f * c.rG[1] * (t1 + t2 + t3);

    KG = line1 + line2 + line3;

    // Ktilde (ORDER==1)
    float Lg = __logf(b) + c.log_mu_c;
    Kt = c.kt_coef * Lg;
}

__global__ __launch_bounds__(256) void pert_evo_kernel(
    const float* __restrict__ alphaS_f,
    const float* __restrict__ p_alphaS_i,
    const float* __restrict__ bT,
    const float* __restrict__ p_mu,
    const float* __restrict__ p_aS_mu,
    const float* __restrict__ r_Gamma,
    const float* __restrict__ r_gamma,
    const float* __restrict__ rbar,
    const float* __restrict__ p_rbar0prime,
    const float* __restrict__ delta,
    float* __restrict__ out, int n)
{
    // ---- wave-uniform constants (addresses uniform -> scalar loads) ----
    const float alphaS_i = p_alphaS_i[0];
    const float mu       = p_mu[0];
    const float aS_mu    = p_aS_mu[0];

    PEConsts c;
    c.rbp = p_rbar0prime[0];
    float dl[4], rbv[4];
#pragma unroll
    for (int j = 0; j < 4; ++j) {
        c.rG[j] = r_Gamma[j];
        c.rg[j] = r_gamma[j];
        rbv[j]  = rbar[j];
        dl[j]   = delta[j];
    }
    c.rb0 = rbv[0];
    c.rb1 = rbv[1];
#pragma unroll
    for (int j = 0; j < 4; ++j) {
        c.d4[j]     = FOUR_PI * dl[j];
        c.logden[j] = __logf(alphaS_i - c.d4[j]);
    }
    const float a0 = alphaS_i * INV_FOUR_PI;
    c.inv_a0   = 1.0f / a0;
    c.inv_di   = 1.0f / dl[1];
    c.dilog_a0 = li2_series(a0 * c.inv_di);
    c.log1m    = __logf(1.0f - a0 * c.inv_di);
    c.coeffs2  = c.rG[1] * c.rb0 - c.rG[0] * rbv[1];
    c.kt_coef  = -8.0f * CF_ * aS_mu;
    c.log_mu_c = __logf(mu) + EG - LN2;

    const int n16 = n >> 4;  // one thread per 16 elements (4 adjacent float4s)
    const int i   = blockIdx.x * blockDim.x + threadIdx.x;

    const float4* a4 = (const float4*)alphaS_f;
    const float4* b4 = (const float4*)bT;
    float4* o0 = (float4*)(out);
    float4* o1 = (float4*)(out + (size_t)n);
    float4* o2 = (float4*)(out + 2 * (size_t)n);
    float4* o3 = (float4*)(out + 3 * (size_t)n);

    if (i < n16) {
        const int base = 4 * i;
        // issue all input loads up front (8 x dwordx4 in flight)
        float4 xa[4], xb[4];
#pragma unroll
        for (int q = 0; q < 4; ++q) xa[q] = a4[base + q];
#pragma unroll
        for (int q = 0; q < 4; ++q) xb[q] = b4[base + q];

        // compute + store in two halves to bound register pressure
#pragma unroll
        for (int h = 0; h < 2; ++h) {
            float eta[8], kg[8], KG[8], Kt[8];
#pragma unroll
            for (int q = 0; q < 2; ++q) {
                const float4 A = xa[2 * h + q];
                const float4 B = xb[2 * h + q];
                float As[4] = {A.x, A.y, A.z, A.w};
                float Bs[4] = {B.x, B.y, B.z, B.w};
#pragma unroll
                for (int v = 0; v < 4; ++v)
                    compute_point(c, As[v], Bs[v],
                                  eta[4 * q + v], kg[4 * q + v],
                                  KG[4 * q + v], Kt[4 * q + v]);
            }
            const int b0 = base + 2 * h;
            o0[b0]     = make_float4(eta[0], eta[1], eta[2], eta[3]);
            o0[b0 + 1] = make_float4(eta[4], eta[5], eta[6], eta[7]);
            o1[b0]     = make_float4(kg[0],  kg[1],  kg[2],  kg[3]);
            o1[b0 + 1] = make_float4(kg[4],  kg[5],  kg[6],  kg[7]);
            o2[b0]     = make_float4(KG[0],  KG[1],  KG[2],  KG[3]);
            o2[b0 + 1] = make_float4(KG[4],  KG[5],  KG[6],  KG[7]);
            o3[b0]     = make_float4(Kt[0],  Kt[1],  Kt[2],  Kt[3]);
            o3[b0 + 1] = make_float4(Kt[4],  Kt[5],  Kt[6],  Kt[7]);
        }
    }

    // tail (n not divisible by 16) — N=8388608 is divisible, kept for safety
    const int tail_start = n16 << 4;
    for (int j = tail_start + i; j < n; j += gridDim.x * blockDim.x) {
        float eta, kg, KG, Kt;
        compute_point(c, alphaS_f[j], bT[j], eta, kg, KG, Kt);
        out[j]               = eta;
        out[j + (size_t)n]   = kg;
        out[j + 2*(size_t)n] = KG;
        out[j + 3*(size_t)n] = Kt;
    }
}

extern "C" void kernel_launch(void* const* d_in, const int* in_sizes, int n_in,
                              void* d_out, int out_size, void* d_ws, size_t ws_size,
                              hipStream_t stream) {
    const float* alphaS_f   = (const float*)d_in[0];
    const float* alphaS_i   = (const float*)d_in[1];
    const float* bT         = (const float*)d_in[2];
    const float* mu         = (const float*)d_in[3];
    const float* aS_mu      = (const float*)d_in[4];
    const float* r_Gamma    = (const float*)d_in[5];
    const float* r_gamma    = (const float*)d_in[6];
    const float* rbar       = (const float*)d_in[7];
    const float* rbar0prime = (const float*)d_in[8];
    const float* delta      = (const float*)d_in[9];
    float* out = (float*)d_out;

    const int n   = in_sizes[0];
    const int n16 = n / 16;
    const int block = 256;
    int grid = (n16 + block - 1) / block;   // one thread per 16 elements
    if (grid < 1) grid = 1;

    pert_evo_kernel<<<grid, block, 0, stream>>>(
        alphaS_f, alphaS_i, bT, mu, aS_mu, r_Gamma, r_gamma, rbar,
        rbar0prime, delta, out, n);
}

// Round 7
// 38.281 us; speedup vs baseline: 1.8167x; 1.8167x over previous
//
#include <hip/hip_runtime.h>
#include <math.h>

#define FOUR_PI     12.566370614359172f
#define INV_FOUR_PI 0.07957747154594767f
#define EG          0.5772156649015329f
#define LN2         0.6931471805599453f
#define CF_         (4.0f / 3.0f)

// Li2(x) = sum_{k>=1} x^k / k^2 ; |x| <= 0.19 here -> 8 terms gives <5e-9 abs err
__device__ __forceinline__ float li2_series(float x) {
    float t = x;
    float s = x;
    t *= x; s = fmaf(t, 0.25f, s);
    t *= x; s = fmaf(t, (1.0f / 9.0f), s);
    t *= x; s = fmaf(t, 0.0625f, s);
    t *= x; s = fmaf(t, 0.04f, s);
    t *= x; s = fmaf(t, (1.0f / 36.0f), s);
    t *= x; s = fmaf(t, (1.0f / 49.0f), s);
    t *= x; s = fmaf(t, 0.015625f, s);
    return s;
}

struct PEConsts {
    float d4[4];        // 4*pi*delta[j]
    float logden[4];    // log(alphaS_i - 4*pi*delta[j])
    float rG[4], rg[4];
    float rb0, rb1;
    float rbp;
    float inv_a0, inv_di;
    float dilog_a0, log1m, coeffs2;
    float kt_coef, log_mu_c;
};

__device__ __forceinline__ void compute_point(const PEConsts& c, float x, float b,
                                              float& eta, float& kg, float& KG, float& Kt) {
    float Lr0 = __logf(x - c.d4[0]) - c.logden[0];
    float Lr1 = __logf(x - c.d4[1]) - c.logden[1];
    float Lr2 = __logf(x - c.d4[2]) - c.logden[2];
    float Lr3 = __logf(x - c.d4[3]) - c.logden[3];

    eta = -0.5f * (c.rG[0] * Lr0 + c.rG[1] * Lr1 + c.rG[2] * Lr2 + c.rG[3] * Lr3);
    kg  = -0.5f * (c.rg[0] * Lr0 + c.rg[1] * Lr1 + c.rg[2] * Lr2 + c.rg[3] * Lr3);

    float aS     = x * INV_FOUR_PI;
    float inv_aS = FOUR_PI / x;

    // line1
    float line1 = 0.25f * c.rG[0] * c.rbp * (inv_aS + (Lr0 - 1.0f) * c.inv_a0)
                + 0.125f * c.rG[0] * c.rb0 * Lr0 * Lr0;
    // line2 (ORDER==1 -> only j=1 term)
    float dilog_aS = li2_series(aS * c.inv_di);
    float line2 = 0.25f * c.coeffs2 * (Lr0 * c.log1m + dilog_aS - c.dilog_a0);
    // line3
    float t1 = 0.5f * c.rb1 * Lr1 * Lr1;
    float t2 = c.rb0 * Lr0 * Lr1;
    float t3 = c.rbp * ((Lr0 - Lr1) * c.inv_di + Lr1 * c.inv_a0);
    float line3 = 0.25f * c.rG[1] * (t1 + t2 + t3);

    KG = line1 + line2 + line3;

    // Ktilde (ORDER==1)
    float Lg = __logf(b) + c.log_mu_c;
    Kt = c.kt_coef * Lg;
}

__global__ __launch_bounds__(256) void pert_evo_kernel(
    const float* __restrict__ alphaS_f,
    const float* __restrict__ p_alphaS_i,
    const float* __restrict__ bT,
    const float* __restrict__ p_mu,
    const float* __restrict__ p_aS_mu,
    const float* __restrict__ r_Gamma,
    const float* __restrict__ r_gamma,
    const float* __restrict__ rbar,
    const float* __restrict__ p_rbar0prime,
    const float* __restrict__ delta,
    float* __restrict__ out, int n)
{
    // ---- wave-uniform constants (addresses uniform -> scalar loads) ----
    const float alphaS_i = p_alphaS_i[0];
    const float mu       = p_mu[0];
    const float aS_mu    = p_aS_mu[0];

    PEConsts c;
    c.rbp = p_rbar0prime[0];
    float dl[4], rbv[4];
#pragma unroll
    for (int j = 0; j < 4; ++j) {
        c.rG[j] = r_Gamma[j];
        c.rg[j] = r_gamma[j];
        rbv[j]  = rbar[j];
        dl[j]   = delta[j];
    }
    c.rb0 = rbv[0];
    c.rb1 = rbv[1];
#pragma unroll
    for (int j = 0; j < 4; ++j) {
        c.d4[j]     = FOUR_PI * dl[j];
        c.logden[j] = __logf(alphaS_i - c.d4[j]);
    }
    const float a0 = alphaS_i * INV_FOUR_PI;
    c.inv_a0   = 1.0f / a0;
    c.inv_di   = 1.0f / dl[1];
    c.dilog_a0 = li2_series(a0 * c.inv_di);
    c.log1m    = __logf(1.0f - a0 * c.inv_di);
    c.coeffs2  = c.rG[1] * c.rb0 - c.rG[0] * rbv[1];
    c.kt_coef  = -8.0f * CF_ * aS_mu;
    c.log_mu_c = __logf(mu) + EG - LN2;

    const int n8 = n >> 3;   // threads needed (8 elements each)
    const int i  = blockIdx.x * blockDim.x + threadIdx.x;

    const float4* a4 = (const float4*)alphaS_f;
    const float4* b4 = (const float4*)bT;
    float4* o0 = (float4*)(out);
    float4* o1 = (float4*)(out + (size_t)n);
    float4* o2 = (float4*)(out + 2 * (size_t)n);
    float4* o3 = (float4*)(out + 3 * (size_t)n);

    if (i < n8) {
        // wave-blocked: each instruction is 64-lane contiguous (1KB);
        // each wave covers a 2KB contiguous span per stream.
        const int lane  = i & 63;
        const int wave  = i >> 6;
        const int base0 = wave * 128 + lane;   // float4 index
        const int base1 = base0 + 64;

        float4 xa0 = a4[base0];
        float4 xb0 = b4[base0];
        float4 xa1 = a4[base1];
        float4 xb1 = b4[base1];

        float xs0[4] = {xa0.x, xa0.y, xa0.z, xa0.w};
        float bs0[4] = {xb0.x, xb0.y, xb0.z, xb0.w};
        float xs1[4] = {xa1.x, xa1.y, xa1.z, xa1.w};
        float bs1[4] = {xb1.x, xb1.y, xb1.z, xb1.w};

        float eta0[4], kg0[4], KG0[4], Kt0[4];
        float eta1[4], kg1[4], KG1[4], Kt1[4];
#pragma unroll
        for (int v = 0; v < 4; ++v)
            compute_point(c, xs0[v], bs0[v], eta0[v], kg0[v], KG0[v], Kt0[v]);
#pragma unroll
        for (int v = 0; v < 4; ++v)
            compute_point(c, xs1[v], bs1[v], eta1[v], kg1[v], KG1[v], Kt1[v]);

        o0[base0] = make_float4(eta0[0], eta0[1], eta0[2], eta0[3]);
        o0[base1] = make_float4(eta1[0], eta1[1], eta1[2], eta1[3]);
        o1[base0] = make_float4(kg0[0],  kg0[1],  kg0[2],  kg0[3]);
        o1[base1] = make_float4(kg1[0],  kg1[1],  kg1[2],  kg1[3]);
        o2[base0] = make_float4(KG0[0],  KG0[1],  KG0[2],  KG0[3]);
        o2[base1] = make_float4(KG1[0],  KG1[1],  KG1[2],  KG1[3]);
        o3[base0] = make_float4(Kt0[0],  Kt0[1],  Kt0[2],  Kt0[3]);
        o3[base1] = make_float4(Kt1[0],  Kt1[1],  Kt1[2],  Kt1[3]);
    }

    // tail (n not divisible by 8) — N=8388608 is divisible, kept for safety
    const int tail_start = n8 << 3;
    for (int j = tail_start + i; j < n; j += gridDim.x * blockDim.x) {
        float eta, kg, KG, Kt;
        compute_point(c, alphaS_f[j], bT[j], eta, kg, KG, Kt);
        out[j]               = eta;
        out[j + (size_t)n]   = kg;
        out[j + 2*(size_t)n] = KG;
        out[j + 3*(size_t)n] = Kt;
    }
}

extern "C" void kernel_launch(void* const* d_in, const int* in_sizes, int n_in,
                              void* d_out, int out_size, void* d_ws, size_t ws_size,
                              hipStream_t stream) {
    const float* alphaS_f   = (const float*)d_in[0];
    const float* alphaS_i   = (const float*)d_in[1];
    const float* bT         = (const float*)d_in[2];
    const float* mu         = (const float*)d_in[3];
    const float* aS_mu      = (const float*)d_in[4];
    const float* r_Gamma    = (const float*)d_in[5];
    const float* r_gamma    = (const float*)d_in[6];
    const float* rbar       = (const float*)d_in[7];
    const float* rbar0prime = (const float*)d_in[8];
    const float* delta      = (const float*)d_in[9];
    float* out = (float*)d_out;

    const int n  = in_sizes[0];
    const int n8 = n / 8;
    const int block = 256;
    int grid = (n8 + block - 1) / block;   // one thread per 8 elements
    if (grid < 1) grid = 1;

    pert_evo_kernel<<<grid, block, 0, stream>>>(
        alphaS_f, alphaS_i, bT, mu, aS_mu, r_Gamma, r_gamma, rbar,
        rbar0prime, delta, out, n);
}

// Round 8
// 38.166 us; speedup vs baseline: 1.8222x; 1.0030x over previous
//
#include <hip/hip_runtime.h>
#include <math.h>

#define FOUR_PI     12.566370614359172f
#define INV_FOUR_PI 0.07957747154594767f
#define EG          0.5772156649015329f
#define LN2         0.6931471805599453f
#define CF_         (4.0f / 3.0f)

// Li2(x) = sum_{k>=1} x^k / k^2 ; |x| <= 0.19 here -> 8 terms gives <5e-9 abs err
__device__ __forceinline__ float li2_series(float x) {
    float t = x;
    float s = x;
    t *= x; s = fmaf(t, 0.25f, s);
    t *= x; s = fmaf(t, (1.0f / 9.0f), s);
    t *= x; s = fmaf(t, 0.0625f, s);
    t *= x; s = fmaf(t, 0.04f, s);
    t *= x; s = fmaf(t, (1.0f / 36.0f), s);
    t *= x; s = fmaf(t, (1.0f / 49.0f), s);
    t *= x; s = fmaf(t, 0.015625f, s);
    return s;
}

struct PEConsts {
    float d4[4];        // 4*pi*delta[j]
    float logden[4];    // log(alphaS_i - 4*pi*delta[j])
    float rG[4], rg[4];
    float rb0, rb1;
    float rbp;
    float inv_a0, inv_di;
    float dilog_a0, log1m, coeffs2;
    float kt_coef, log_mu_c;
};

__device__ __forceinline__ void compute_point(const PEConsts& c, float x, float b,
                                              float& eta, float& kg, float& KG, float& Kt) {
    float Lr0 = __logf(x - c.d4[0]) - c.logden[0];
    float Lr1 = __logf(x - c.d4[1]) - c.logden[1];
    float Lr2 = __logf(x - c.d4[2]) - c.logden[2];
    float Lr3 = __logf(x - c.d4[3]) - c.logden[3];

    eta = -0.5f * (c.rG[0] * Lr0 + c.rG[1] * Lr1 + c.rG[2] * Lr2 + c.rG[3] * Lr3);
    kg  = -0.5f * (c.rg[0] * Lr0 + c.rg[1] * Lr1 + c.rg[2] * Lr2 + c.rg[3] * Lr3);

    float aS     = x * INV_FOUR_PI;
    float inv_aS = FOUR_PI / x;

    // line1
    float line1 = 0.25f * c.rG[0] * c.rbp * (inv_aS + (Lr0 - 1.0f) * c.inv_a0)
                + 0.125f * c.rG[0] * c.rb0 * Lr0 * Lr0;
    // line2 (ORDER==1 -> only j=1 term)
    float dilog_aS = li2_series(aS * c.inv_di);
    float line2 = 0.25f * c.coeffs2 * (Lr0 * c.log1m + dilog_aS - c.dilog_a0);
    // line3
    float t1 = 0.5f * c.rb1 * Lr1 * Lr1;
    float t2 = c.rb0 * Lr0 * Lr1;
    float t3 = c.rbp * ((Lr0 - Lr1) * c.inv_di + Lr1 * c.inv_a0);
    float line3 = 0.25f * c.rG[1] * (t1 + t2 + t3);

    KG = line1 + line2 + line3;

    // Ktilde (ORDER==1)
    float Lg = __logf(b) + c.log_mu_c;
    Kt = c.kt_coef * Lg;
}

__global__ __launch_bounds__(256) void pert_evo_kernel(
    const float* __restrict__ alphaS_f,
    const float* __restrict__ p_alphaS_i,
    const float* __restrict__ bT,
    const float* __restrict__ p_mu,
    const float* __restrict__ p_aS_mu,
    const float* __restrict__ r_Gamma,
    const float* __restrict__ r_gamma,
    const float* __restrict__ rbar,
    const float* __restrict__ p_rbar0prime,
    const float* __restrict__ delta,
    float* __restrict__ out, int n)
{
    // ---- wave-uniform constants (addresses uniform -> scalar loads) ----
    const float alphaS_i = p_alphaS_i[0];
    const float mu       = p_mu[0];
    const float aS_mu    = p_aS_mu[0];

    PEConsts c;
    c.rbp = p_rbar0prime[0];
    float dl[4], rbv[4];
#pragma unroll
    for (int j = 0; j < 4; ++j) {
        c.rG[j] = r_Gamma[j];
        c.rg[j] = r_gamma[j];
        rbv[j]  = rbar[j];
        dl[j]   = delta[j];
    }
    c.rb0 = rbv[0];
    c.rb1 = rbv[1];
#pragma unroll
    for (int j = 0; j < 4; ++j) {
        c.d4[j]     = FOUR_PI * dl[j];
        c.logden[j] = __logf(alphaS_i - c.d4[j]);
    }
    const float a0 = alphaS_i * INV_FOUR_PI;
    c.inv_a0   = 1.0f / a0;
    c.inv_di   = 1.0f / dl[1];
    c.dilog_a0 = li2_series(a0 * c.inv_di);
    c.log1m    = __logf(1.0f - a0 * c.inv_di);
    c.coeffs2  = c.rG[1] * c.rb0 - c.rG[0] * rbv[1];
    c.kt_coef  = -8.0f * CF_ * aS_mu;
    c.log_mu_c = __logf(mu) + EG - LN2;

    const int n16 = n >> 4;  // threads needed (16 elements each)
    const int i   = blockIdx.x * blockDim.x + threadIdx.x;

    const float4* a4 = (const float4*)alphaS_f;
    const float4* b4 = (const float4*)bT;
    float4* o0 = (float4*)(out);
    float4* o1 = (float4*)(out + (size_t)n);
    float4* o2 = (float4*)(out + 2 * (size_t)n);
    float4* o3 = (float4*)(out + 3 * (size_t)n);

    if (i < n16) {
        // wave-blocked: each instruction is 64-lane contiguous (1KB);
        // each wave covers a 4KB contiguous span per stream.
        const int lane = i & 63;
        const int wave = i >> 6;
        const int base = wave * 256 + lane;    // float4 index; quads at +0,+64,+128,+192

        float4 xa[4], xb[4];
#pragma unroll
        for (int q = 0; q < 4; ++q) xa[q] = a4[base + 64 * q];
#pragma unroll
        for (int q = 0; q < 4; ++q) xb[q] = b4[base + 64 * q];

#pragma unroll
        for (int q = 0; q < 4; ++q) {
            float As[4] = {xa[q].x, xa[q].y, xa[q].z, xa[q].w};
            float Bs[4] = {xb[q].x, xb[q].y, xb[q].z, xb[q].w};
            float eta[4], kg[4], KG[4], Kt[4];
#pragma unroll
            for (int v = 0; v < 4; ++v)
                compute_point(c, As[v], Bs[v], eta[v], kg[v], KG[v], Kt[v]);
            const int bq = base + 64 * q;
            o0[bq] = make_float4(eta[0], eta[1], eta[2], eta[3]);
            o1[bq] = make_float4(kg[0],  kg[1],  kg[2],  kg[3]);
            o2[bq] = make_float4(KG[0],  KG[1],  KG[2],  KG[3]);
            o3[bq] = make_float4(Kt[0],  Kt[1],  Kt[2],  Kt[3]);
        }
    }

    // tail (n not divisible by 16) — N=8388608 is divisible, kept for safety
    const int tail_start = n16 << 4;
    for (int j = tail_start + i; j < n; j += gridDim.x * blockDim.x) {
        float eta, kg, KG, Kt;
        compute_point(c, alphaS_f[j], bT[j], eta, kg, KG, Kt);
        out[j]               = eta;
        out[j + (size_t)n]   = kg;
        out[j + 2*(size_t)n] = KG;
        out[j + 3*(size_t)n] = Kt;
    }
}

extern "C" void kernel_launch(void* const* d_in, const int* in_sizes, int n_in,
                              void* d_out, int out_size, void* d_ws, size_t ws_size,
                              hipStream_t stream) {
    const float* alphaS_f   = (const float*)d_in[0];
    const float* alphaS_i   = (const float*)d_in[1];
    const float* bT         = (const float*)d_in[2];
    const float* mu         = (const float*)d_in[3];
    const float* aS_mu      = (const float*)d_in[4];
    const float* r_Gamma    = (const float*)d_in[5];
    const float* r_gamma    = (const float*)d_in[6];
    const float* rbar       = (const float*)d_in[7];
    const float* rbar0prime = (const float*)d_in[8];
    const float* delta      = (const float*)d_in[9];
    float* out = (float*)d_out;

    const int n   = in_sizes[0];
    const int n16 = n / 16;
    const int block = 256;
    int grid = (n16 + block - 1) / block;   // one thread per 16 elements
    if (grid < 1) grid = 1;

    pert_evo_kernel<<<grid, block, 0, stream>>>(
        alphaS_f, alphaS_i, bT, mu, aS_mu, r_Gamma, r_gamma, rbar,
        rbar0prime, delta, out, n);
}